// Round 15
// baseline (69.787 us; speedup 1.0000x reference)
//
#include <hip/hip_runtime.h>

#define BATCH 1024
#define INSZ 4096
#define NH 8
#define TPB 256
#define LDT 40   // xn [128][32] padded stride

typedef __attribute__((ext_vector_type(8))) __bf16 bf16x8;
typedef __attribute__((ext_vector_type(4))) __bf16 bf16x4;
typedef __attribute__((ext_vector_type(4))) float f32x4;

// ws layout (bf16 elems):
//   M  [0,8192)      per-head M_h[e'][e] = CQ * sum_f Wk[f][e]*Wq[f][e']  (8x 32x32)
//   C  [8192,8704)   c padded [16][32]: rows h<8 = CQ*Wq_h^T*bk_h, rows 8-15 = 0
//   wv [16384,24576) bf16 copy of wv
//   wo [24576,32768) bf16 copy of wo
// LDS layout (bf16 elems):
//   PO [0,16384)     P [128][128] swizzled; xn [0,5120) overlays (dies pre-loop)
//   V0 [16384,20480) vT parity0 [32][128] swizzled
//   V1 [20480,24576) vT parity1
//   SD [24576,26624) s[8 heads][128 i] f32 (query-bias term, computed once)
//   RD [26624,26656) LN reduction scratch
// Total 26656 elems = 53312 B -> 2 blocks/CU.
#define PO 0
#define V0 16384
#define V1 20480
#define SD 24576
#define RD 26624

// 1/sqrt(32) * log2(e). Softmax over QUERY axis i: all score terms constant
// in i cancel exactly, so scores reduce to xn_i M_h xn_j^T + c_h.xn_i.
#define CQ 0.25505644061151687f

__global__ void cvt_vo(const float* __restrict__ wv, const float* __restrict__ wo,
                       __bf16* __restrict__ ws) {
  int i = blockIdx.x * blockDim.x + threadIdx.x;  // 0..16383
  ws[16384 + i] = (__bf16)((i < 8192) ? wv[i] : wo[i - 8192]);
}

// One block per head: M_h = CQ*Wk_h^T*Wq_h (bf16), c_h = CQ*Wq_h^T*bk_h.
__global__ void prep_m(const float* __restrict__ wq, const float* __restrict__ wk,
                       const float* __restrict__ bk, __bf16* __restrict__ ws) {
  __shared__ float Q[1024], K[1024];
  const int h = blockIdx.x, t = threadIdx.x;
  for (int z = t; z < 1024; z += TPB) { Q[z] = wq[h * 1024 + z]; K[z] = wk[h * 1024 + z]; }
  __syncthreads();
#pragma unroll
  for (int z = 0; z < 4; ++z) {
    int idx = t * 4 + z;            // 0..1023
    int ep = idx >> 5, e = idx & 31;
    float acc = 0.f;
#pragma unroll
    for (int f = 0; f < 32; ++f) acc += K[f * 32 + e] * Q[f * 32 + ep];
    ws[h * 1024 + ep * 32 + e] = (__bf16)(acc * CQ);  // M[e'][e]
  }
  if (t < 32) {
    float acc = 0.f;
#pragma unroll
    for (int f = 0; f < 32; ++f) acc += Q[f * 32 + t] * bk[h * 32 + f];
    ws[8192 + h * 32 + t] = (__bf16)(acc * CQ);       // C row h
  }
  if (h == 0) ws[8448 + t] = (__bf16)0.f;             // C rows 8..15 zero
}

// 16-lane butterfly sum on the VALU pipe (DPP), no LDS traffic.
__device__ __forceinline__ float row_reduce_add16(float v) {
  int t;
  t = __builtin_amdgcn_update_dpp(0, __float_as_int(v), 0xB1, 0xF, 0xF, true);
  v += __int_as_float(t);
  t = __builtin_amdgcn_update_dpp(0, __float_as_int(v), 0x4E, 0xF, 0xF, true);
  v += __int_as_float(t);
  t = __builtin_amdgcn_update_dpp(0, __float_as_int(v), 0x141, 0xF, 0xF, true);
  v += __int_as_float(t);
  t = __builtin_amdgcn_update_dpp(0, __float_as_int(v), 0x140, 0xF, 0xF, true);
  v += __int_as_float(t);
  return v;
}

__global__ __launch_bounds__(TPB, 2) void mha_fused(
    const float* __restrict__ x, const float* __restrict__ gamma,
    const float* __restrict__ beta, const float* __restrict__ bv,
    const float* __restrict__ bo, const __bf16* __restrict__ wbf,
    float* __restrict__ out) {
  __shared__ __align__(16) __bf16 R[26656];  // 53312 B

  const int b = blockIdx.x;
  const int tid = threadIdx.x;
  const int lane = tid & 63;
  const int wid = tid >> 6;   // 4 waves; wave w owns key-rows j in [32w, 32w+32)
  const int l15 = lane & 15;
  const int lh = lane >> 4;   // 0..3
  const int sw = (l15 & 7) << 3;  // XOR swizzle (elems) for 256B-stride tiles

  const __bf16* wvb = wbf + 16384;
  const __bf16* wob = wbf + 24576;  // [32][256] row-major

  const float* xb = x + b * INSZ;
  const f32x4 fz = {0.f, 0.f, 0.f, 0.f};

  float* red2 = (float*)&R[RD];
  float* sp = (float*)&R[SD];  // s[h][i]

  // ---------------- LayerNorm ----------------
  float xv[16];
  float s = 0.f, sq = 0.f;
#pragma unroll
  for (int i = 0; i < 4; ++i) {
    float4 a = ((const float4*)(xb + tid * 16))[i];
    xv[4 * i] = a.x; xv[4 * i + 1] = a.y; xv[4 * i + 2] = a.z; xv[4 * i + 3] = a.w;
  }
#pragma unroll
  for (int i = 0; i < 16; ++i) { s += xv[i]; sq += xv[i] * xv[i]; }
#pragma unroll
  for (int o = 32; o > 0; o >>= 1) { s += __shfl_down(s, o); sq += __shfl_down(sq, o); }
  if (lane == 0) { red2[wid] = s; red2[4 + wid] = sq; }
  __syncthreads();
  s = red2[0] + red2[1] + red2[2] + red2[3];
  sq = red2[4] + red2[5] + red2[6] + red2[7];
  const float mu = s * (1.f / INSZ);
  const float var = fmaxf(sq * (1.f / INSZ) - mu * mu, 0.f);
  const float rs = rsqrtf(var + 1e-5f);
  {
    int base = tid * 16;
#pragma unroll
    for (int i = 0; i < 4; ++i) {
      float4 g4 = ((const float4*)(gamma + base))[i];
      float4 b4 = ((const float4*)(beta + base))[i];
      float gg[4] = {g4.x, g4.y, g4.z, g4.w};
      float bb[4] = {b4.x, b4.y, b4.z, b4.w};
#pragma unroll
      for (int k = 0; k < 4; ++k) {
        int idx = base + 4 * i + k;
        float xn = (xv[4 * i + k] - mu) * rs * gg[k] + bb[k];
        R[PO + (idx >> 5) * LDT + (idx & 31)] = (__bf16)xn;
      }
    }
  }
  __syncthreads();  // P1: xn visible to all waves (xq spans all 128 rows)

  const int r0 = wid * 32;

  // xn B-frags for scores, PERMUTED cols (virtual k u -> e'(u)=(u>=4)*16+lh*4+(u&3)),
  // all 128 query rows — head-invariant, live in registers forever.
  bf16x8 xq[8];
#pragma unroll
  for (int it = 0; it < 8; ++it) {
    bf16x4 lo = *(const bf16x4*)&R[PO + (it * 16 + l15) * LDT + lh * 4];
    bf16x4 hi = *(const bf16x4*)&R[PO + (it * 16 + l15) * LDT + 16 + lh * 4];
#pragma unroll
    for (int u = 0; u < 4; ++u) { xq[it][u] = lo[u]; xq[it][4 + u] = hi[u]; }
  }
  // xn natural frags of own rows (A/B-op for t-proj, v-proj, s-MFMA).
  bf16x8 tA0 = *(const bf16x8*)&R[PO + (r0 + l15) * LDT + lh * 8];
  bf16x8 tA1 = *(const bf16x8*)&R[PO + (r0 + 16 + l15) * LDT + lh * 8];
  // xn LDS dies here (P may overwrite after barrier A(0)).

  // s[h][i] = c_h . xn_i — one MFMA pair: D[i][h] = mfma(xn_own, Cpad)
  {
    bf16x8 cf = *(const bf16x8*)&wbf[8192 + l15 * 32 + lh * 8];
    f32x4 s0 = __builtin_amdgcn_mfma_f32_16x16x32_bf16(tA0, cf, fz, 0, 0, 0);
    f32x4 s1 = __builtin_amdgcn_mfma_f32_16x16x32_bf16(tA1, cf, fz, 0, 0, 0);
    if (l15 < 8) {
#pragma unroll
      for (int r = 0; r < 4; ++r) {
        sp[l15 * 128 + r0 + lh * 4 + r] = s0[r];
        sp[l15 * 128 + r0 + 16 + lh * 4 + r] = s1[r];
      }
    }
  }

  // oacc[mt][nt]: D[q][e'], q=r0+mt*16+lh*4+r, e'=nt*16+l15; seeded with bo.
  f32x4 oacc[2][2];
  {
    float b0 = bo[l15], b1 = bo[16 + l15];
#pragma unroll
    for (int mt = 0; mt < 2; ++mt) {
      oacc[mt][0] = f32x4{b0, b0, b0, b0};
      oacc[mt][1] = f32x4{b1, b1, b1, b1};
    }
  }

  // t A-frags (scores), packed straight from t-proj MFMA output regs.
  bf16x8 tka0, tka1;

  // Per head: t-proj (wave-local, reg-packed) + v-proj (vT staged cross-wave).
  auto do_proj = [&](int hh, int vo) {
    const __bf16* Mh = wbf + hh * 1024;
    bf16x8 m0 = *(const bf16x8*)&Mh[(l15) * 32 + lh * 8];       // e' rows 0-15
    bf16x8 m1 = *(const bf16x8*)&Mh[(16 + l15) * 32 + lh * 8];  // e' rows 16-31
    // t^T[e'][j] = mfma(M, xn_own): D cols = j = l15(+st*16), rows = e' reg-held.
    f32x4 d00 = __builtin_amdgcn_mfma_f32_16x16x32_bf16(m0, tA0, fz, 0, 0, 0);
    f32x4 d01 = __builtin_amdgcn_mfma_f32_16x16x32_bf16(m0, tA1, fz, 0, 0, 0);
    f32x4 d10 = __builtin_amdgcn_mfma_f32_16x16x32_bf16(m1, tA0, fz, 0, 0, 0);
    f32x4 d11 = __builtin_amdgcn_mfma_f32_16x16x32_bf16(m1, tA1, fz, 0, 0, 0);
    // tka_st[u] = t[j=r0+st*16+l15][e'(u)], e'(u) = (u>=4)*16 + lh*4 + (u&3).
#pragma unroll
    for (int u = 0; u < 4; ++u) {
      tka0[u] = (__bf16)d00[u]; tka0[4 + u] = (__bf16)d10[u];
      tka1[u] = (__bf16)d01[u]; tka1[4 + u] = (__bf16)d11[u];
    }
    // v-proj: D[s][f], packed store into swizzled vT[f][s].
#pragma unroll
    for (int nt = 0; nt < 2; ++nt) {
      int f0 = hh * 32 + nt * 16;
      bf16x8 wvf = *(const bf16x8*)&wvb[(f0 + l15) * 32 + lh * 8];
      float bvs = bv[f0 + l15];
      f32x4 bv4 = {bvs, bvs, bvs, bvs};
#pragma unroll
      for (int mt = 0; mt < 2; ++mt) {
        bf16x8 tA = (mt == 0) ? tA0 : tA1;
        f32x4 dv = __builtin_amdgcn_mfma_f32_16x16x32_bf16(tA, wvf, bv4, 0, 0, 0);
        bf16x4 pv;
#pragma unroll
        for (int r = 0; r < 4; ++r) pv[r] = (__bf16)dv[r];
        *(bf16x4*)&R[vo + (nt * 16 + l15) * 128 + ((r0 + mt * 16 + lh * 4) ^ sw)] = pv;
      }
    }
  };

  do_proj(0, V0);
  __syncthreads();  // P2: s + vT[0] visible

  for (int h = 0; h < NH; ++h) {
    const int p = h & 1;
    const int vo = p ? V1 : V0;

    // ---------- [1] scoresT = t·xn^T : 100% register operands ----------
    // st_[mt][it]: D[j][i], j = r0+mt*16+lh*4+r, i = it*16+l15  (same as r9)
    f32x4 st_[2][8];
    __builtin_amdgcn_s_setprio(1);
#pragma unroll
    for (int it = 0; it < 8; ++it) {
      st_[0][it] = __builtin_amdgcn_mfma_f32_16x16x32_bf16(tka0, xq[it], fz, 0, 0, 0);
      st_[1][it] = __builtin_amdgcn_mfma_f32_16x16x32_bf16(tka1, xq[it], fz, 0, 0, 0);
    }
    __builtin_amdgcn_s_setprio(0);

    // ---------- [2] project NEXT head (fills scores MFMA latency) ----------
    if (h < NH - 1) do_proj(h + 1, p ? V0 : V1);

    // ---------- [3] softmax over query axis: + s_i bias, exp2, DPP sums ----------
    float sv[8];
#pragma unroll
    for (int it = 0; it < 8; ++it) sv[it] = sp[h * 128 + it * 16 + l15];
    float inv[2][4];
#pragma unroll
    for (int mt = 0; mt < 2; ++mt)
#pragma unroll
      for (int r = 0; r < 4; ++r) {
        float ssum = 0.f;
#pragma unroll
        for (int it = 0; it < 8; ++it) {
          float e = __builtin_amdgcn_exp2f(st_[mt][it][r] + sv[it]);
          st_[mt][it][r] = e;
          ssum += e;
        }
        ssum = row_reduce_add16(ssum);
        inv[mt][r] = __builtin_amdgcn_rcpf(ssum);
      }

    __syncthreads();  // A: PV(h-1) P-reads done; vT[p] stores visible

    // ---------- [4.5] va prefetch (vT[p] stable since before A) ----------
    bf16x8 va[2][4];
#pragma unroll
    for (int kc = 0; kc < 4; ++kc) {
      va[0][kc] = *(const bf16x8*)&R[vo + (l15) * 128 + ((kc * 32 + lh * 8) ^ sw)];
      va[1][kc] = *(const bf16x8*)&R[vo + (16 + l15) * 128 + ((kc * 32 + lh * 8) ^ sw)];
    }

    // ---------- [5] P store: normalized, [query][key] swizzled, packed b64 ----------
#pragma unroll
    for (int mt = 0; mt < 2; ++mt)
#pragma unroll
      for (int it = 0; it < 8; ++it) {
        bf16x4 pp;
#pragma unroll
        for (int r = 0; r < 4; ++r) pp[r] = (__bf16)(st_[mt][it][r] * inv[mt][r]);
        *(bf16x4*)&R[PO + (it * 16 + l15) * 128 + ((r0 + mt * 16 + lh * 4) ^ sw)] = pp;
      }
    __syncthreads();  // B: P ready

    // ---------- [7] PV: D[e][q] = vT·P^T ----------
    f32x4 p2[2][2];
#pragma unroll
    for (int i = 0; i < 2; ++i)
#pragma unroll
      for (int j = 0; j < 2; ++j) p2[i][j] = fz;
    __builtin_amdgcn_s_setprio(1);
#pragma unroll
    for (int kc = 0; kc < 4; ++kc) {
      bf16x8 pb0 = *(const bf16x8*)&R[PO + (r0 + l15) * 128 + ((kc * 32 + lh * 8) ^ sw)];
      bf16x8 pb1 = *(const bf16x8*)&R[PO + (r0 + 16 + l15) * 128 + ((kc * 32 + lh * 8) ^ sw)];
      p2[0][0] = __builtin_amdgcn_mfma_f32_16x16x32_bf16(va[0][kc], pb0, p2[0][0], 0, 0, 0);
      p2[0][1] = __builtin_amdgcn_mfma_f32_16x16x32_bf16(va[0][kc], pb1, p2[0][1], 0, 0, 0);
      p2[1][0] = __builtin_amdgcn_mfma_f32_16x16x32_bf16(va[1][kc], pb0, p2[1][0], 0, 0, 0);
      p2[1][1] = __builtin_amdgcn_mfma_f32_16x16x32_bf16(va[1][kc], pb1, p2[1][1], 0, 0, 0);
    }
    __builtin_amdgcn_s_setprio(0);

    // ---------- [8] outproj from registers (permuted-k, no LDS) ----------
    // virtual k u <-> e = (u>=4)*16 + lh*4 + (u&3); A and B share it.
    {
      bf16x8 pa0, pa1;
#pragma unroll
      for (int u = 0; u < 4; ++u) {
        pa0[u] = (__bf16)p2[0][0][u]; pa0[4 + u] = (__bf16)p2[1][0][u];
        pa1[u] = (__bf16)p2[0][1][u]; pa1[4 + u] = (__bf16)p2[1][1][u];
      }
      bf16x4 w0lo = *(const bf16x4*)&wob[(l15) * 256 + h * 32 + lh * 4];
      bf16x4 w0hi = *(const bf16x4*)&wob[(l15) * 256 + h * 32 + 16 + lh * 4];
      bf16x4 w1lo = *(const bf16x4*)&wob[(16 + l15) * 256 + h * 32 + lh * 4];
      bf16x4 w1hi = *(const bf16x4*)&wob[(16 + l15) * 256 + h * 32 + 16 + lh * 4];
      bf16x8 wof0, wof1;
#pragma unroll
      for (int u = 0; u < 4; ++u) {
        wof0[u] = w0lo[u]; wof0[4 + u] = w0hi[u];
        wof1[u] = w1lo[u]; wof1[4 + u] = w1hi[u];
      }
      oacc[0][0] = __builtin_amdgcn_mfma_f32_16x16x32_bf16(pa0, wof0, oacc[0][0], 0, 0, 0);
      oacc[0][1] = __builtin_amdgcn_mfma_f32_16x16x32_bf16(pa0, wof1, oacc[0][1], 0, 0, 0);
      oacc[1][0] = __builtin_amdgcn_mfma_f32_16x16x32_bf16(pa1, wof0, oacc[1][0], 0, 0, 0);
      oacc[1][1] = __builtin_amdgcn_mfma_f32_16x16x32_bf16(pa1, wof1, oacc[1][1], 0, 0, 0);
    }
    // No trailing barrier: barrier A(h+1) separates PV(h) P-reads from
    // P-stores(h+1); vT double-buffered across two barriers.
  }

  // ---------------- epilogue: + x (bo already seeded) ----------------
#pragma unroll
  for (int mt = 0; mt < 2; ++mt)
#pragma unroll
    for (int nt = 0; nt < 2; ++nt)
#pragma unroll
      for (int r = 0; r < 4; ++r) {
        int s_ = r0 + mt * 16 + lh * 4 + r;
        int e_ = nt * 16 + l15;
        int idx = s_ * 32 + e_;
        out[b * INSZ + idx] = oacc[mt][nt][r] + xb[idx];
      }
}

extern "C" void kernel_launch(void* const* d_in, const int* in_sizes, int n_in,
                              void* d_out, int out_size, void* d_ws, size_t ws_size,
                              hipStream_t stream) {
  const float* x = (const float*)d_in[0];
  const float* gamma = (const float*)d_in[1];
  const float* beta = (const float*)d_in[2];
  const float* wq = (const float*)d_in[3];
  const float* bk = (const float*)d_in[6];
  const float* wk = (const float*)d_in[5];
  const float* wv = (const float*)d_in[7];
  const float* bv = (const float*)d_in[8];
  const float* wo = (const float*)d_in[9];
  const float* bo = (const float*)d_in[10];
  float* out = (float*)d_out;
  __bf16* wsb = (__bf16*)d_ws;

  cvt_vo<<<64, 256, 0, stream>>>(wv, wo, wsb);
  prep_m<<<8, 256, 0, stream>>>(wq, wk, bk, wsb);
  mha_fused<<<BATCH, TPB, 0, stream>>>(x, gamma, beta, bv, bo, wsb, out);
}

// Round 16
// 67.273 us; speedup vs baseline: 1.0374x; 1.0374x over previous
//
#include <hip/hip_runtime.h>

#define BATCH 1024
#define INSZ 4096
#define NH 8
#define TPB 256
#define LDT 40   // xn [128][32] padded stride

typedef __attribute__((ext_vector_type(8))) __bf16 bf16x8;
typedef __attribute__((ext_vector_type(4))) __bf16 bf16x4;
typedef __attribute__((ext_vector_type(4))) float f32x4;

// ws layout (bf16 elems):
//   M  [0,8192)      per-head M_h[e'][e] = CQ * sum_f Wk[f][e]*Wq[f][e']  (8x 32x32)
//   C  [8192,8704)   c padded [16][32]: rows h<8 = CQ*Wq_h^T*bk_h, rows 8-15 = 0
//   wv [16384,24576) bf16 copy of wv
//   wo [24576,32768) bf16 copy of wo
// LDS layout (bf16 elems):
//   PO [0,16384)     P [128][128] swizzled; xn [0,5120) overlays (dies pre-loop)
//   V0 [16384,20480) vT parity0 [32][128] swizzled
//   V1 [20480,24576) vT parity1
//   SD [24576,26624) s[8 heads][128 i] f32 (query-bias term, computed once)
//   RD [26624,26656) LN reduction scratch
// Total 26656 elems = 53312 B -> 2 blocks/CU.
#define PO 0
#define V0 16384
#define V1 20480
#define SD 24576
#define RD 26624

// 1/sqrt(32) * log2(e). Softmax over QUERY axis i: all score terms constant
// in i cancel exactly, so scores reduce to xn_i M_h xn_j^T + c_h.xn_i.
#define CQ 0.25505644061151687f

// ONE prep kernel (72 blocks): blocks 0-63 convert wv/wo to bf16; blocks
// 64-71 compute M_h = CQ*Wk_h^T*Wq_h and c_h = CQ*Wq_h^T*bk_h. Disjoint ws
// ranges -> safe to fuse; saves one in-graph kernel launch per timed replay.
__global__ void prep(const float* __restrict__ wq, const float* __restrict__ wk,
                     const float* __restrict__ bk, const float* __restrict__ wv,
                     const float* __restrict__ wo, __bf16* __restrict__ ws) {
  const int t = threadIdx.x;
  if (blockIdx.x < 64) {
    int i = blockIdx.x * TPB + t;  // 0..16383
    ws[16384 + i] = (__bf16)((i < 8192) ? wv[i] : wo[i - 8192]);
    return;
  }
  __shared__ float Q[1024], K[1024];
  const int h = blockIdx.x - 64;
  for (int z = t; z < 1024; z += TPB) { Q[z] = wq[h * 1024 + z]; K[z] = wk[h * 1024 + z]; }
  __syncthreads();
#pragma unroll
  for (int z = 0; z < 4; ++z) {
    int idx = t * 4 + z;            // 0..1023
    int ep = idx >> 5, e = idx & 31;
    float acc = 0.f;
#pragma unroll
    for (int f = 0; f < 32; ++f) acc += K[f * 32 + e] * Q[f * 32 + ep];
    ws[h * 1024 + ep * 32 + e] = (__bf16)(acc * CQ);  // M[e'][e]
  }
  if (t < 32) {
    float acc = 0.f;
#pragma unroll
    for (int f = 0; f < 32; ++f) acc += Q[f * 32 + t] * bk[h * 32 + f];
    ws[8192 + h * 32 + t] = (__bf16)(acc * CQ);       // C row h
  }
  if (h == 0) ws[8448 + t] = (__bf16)0.f;             // C rows 8..15 zero
}

// 16-lane butterfly sum on the VALU pipe (DPP), no LDS traffic.
__device__ __forceinline__ float row_reduce_add16(float v) {
  int t;
  t = __builtin_amdgcn_update_dpp(0, __float_as_int(v), 0xB1, 0xF, 0xF, true);
  v += __int_as_float(t);
  t = __builtin_amdgcn_update_dpp(0, __float_as_int(v), 0x4E, 0xF, 0xF, true);
  v += __int_as_float(t);
  t = __builtin_amdgcn_update_dpp(0, __float_as_int(v), 0x141, 0xF, 0xF, true);
  v += __int_as_float(t);
  t = __builtin_amdgcn_update_dpp(0, __float_as_int(v), 0x140, 0xF, 0xF, true);
  v += __int_as_float(t);
  return v;
}

__global__ __launch_bounds__(TPB, 2) void mha_fused(
    const float* __restrict__ x, const float* __restrict__ gamma,
    const float* __restrict__ beta, const float* __restrict__ bv,
    const float* __restrict__ bo, const __bf16* __restrict__ wbf,
    float* __restrict__ out) {
  __shared__ __align__(16) __bf16 R[26656];  // 53312 B

  const int b = blockIdx.x;
  const int tid = threadIdx.x;
  const int lane = tid & 63;
  const int wid = tid >> 6;   // 4 waves; wave w owns key-rows j in [32w, 32w+32)
  const int l15 = lane & 15;
  const int lh = lane >> 4;   // 0..3
  const int sw = (l15 & 7) << 3;  // XOR swizzle (elems) for 256B-stride tiles

  const __bf16* wvb = wbf + 16384;
  const __bf16* wob = wbf + 24576;  // [32][256] row-major

  const float* xb = x + b * INSZ;
  const f32x4 fz = {0.f, 0.f, 0.f, 0.f};

  float* red2 = (float*)&R[RD];
  float* sp = (float*)&R[SD];  // s[h][i]

  // ---------------- LayerNorm ----------------
  float xv[16];
  float s = 0.f, sq = 0.f;
#pragma unroll
  for (int i = 0; i < 4; ++i) {
    float4 a = ((const float4*)(xb + tid * 16))[i];
    xv[4 * i] = a.x; xv[4 * i + 1] = a.y; xv[4 * i + 2] = a.z; xv[4 * i + 3] = a.w;
  }
#pragma unroll
  for (int i = 0; i < 16; ++i) { s += xv[i]; sq += xv[i] * xv[i]; }
#pragma unroll
  for (int o = 32; o > 0; o >>= 1) { s += __shfl_down(s, o); sq += __shfl_down(sq, o); }
  if (lane == 0) { red2[wid] = s; red2[4 + wid] = sq; }
  __syncthreads();
  s = red2[0] + red2[1] + red2[2] + red2[3];
  sq = red2[4] + red2[5] + red2[6] + red2[7];
  const float mu = s * (1.f / INSZ);
  const float var = fmaxf(sq * (1.f / INSZ) - mu * mu, 0.f);
  const float rs = rsqrtf(var + 1e-5f);
  {
    int base = tid * 16;
#pragma unroll
    for (int i = 0; i < 4; ++i) {
      float4 g4 = ((const float4*)(gamma + base))[i];
      float4 b4 = ((const float4*)(beta + base))[i];
      float gg[4] = {g4.x, g4.y, g4.z, g4.w};
      float bb[4] = {b4.x, b4.y, b4.z, b4.w};
#pragma unroll
      for (int k = 0; k < 4; ++k) {
        int idx = base + 4 * i + k;
        float xn = (xv[4 * i + k] - mu) * rs * gg[k] + bb[k];
        R[PO + (idx >> 5) * LDT + (idx & 31)] = (__bf16)xn;
      }
    }
  }
  __syncthreads();  // P1: xn visible to all waves (xq spans all 128 rows)

  const int r0 = wid * 32;

  // xn B-frags for scores, PERMUTED cols (virtual k u -> e'(u)=(u>=4)*16+lh*4+(u&3)),
  // all 128 query rows — head-invariant, live in registers forever.
  bf16x8 xq[8];
#pragma unroll
  for (int it = 0; it < 8; ++it) {
    bf16x4 lo = *(const bf16x4*)&R[PO + (it * 16 + l15) * LDT + lh * 4];
    bf16x4 hi = *(const bf16x4*)&R[PO + (it * 16 + l15) * LDT + 16 + lh * 4];
#pragma unroll
    for (int u = 0; u < 4; ++u) { xq[it][u] = lo[u]; xq[it][4 + u] = hi[u]; }
  }
  // xn natural frags of own rows (A/B-op for t-proj, v-proj, s-MFMA).
  bf16x8 tA0 = *(const bf16x8*)&R[PO + (r0 + l15) * LDT + lh * 8];
  bf16x8 tA1 = *(const bf16x8*)&R[PO + (r0 + 16 + l15) * LDT + lh * 8];
  // xn LDS dies here (P may overwrite after barrier A(0)).

  // s[h][i] = c_h . xn_i — one MFMA pair: D[i][h] = mfma(xn_own, Cpad)
  {
    bf16x8 cf = *(const bf16x8*)&wbf[8192 + l15 * 32 + lh * 8];
    f32x4 s0 = __builtin_amdgcn_mfma_f32_16x16x32_bf16(tA0, cf, fz, 0, 0, 0);
    f32x4 s1 = __builtin_amdgcn_mfma_f32_16x16x32_bf16(tA1, cf, fz, 0, 0, 0);
    if (l15 < 8) {
#pragma unroll
      for (int r = 0; r < 4; ++r) {
        sp[l15 * 128 + r0 + lh * 4 + r] = s0[r];
        sp[l15 * 128 + r0 + 16 + lh * 4 + r] = s1[r];
      }
    }
  }

  // oacc[mt][nt]: D[q][e'], q=r0+mt*16+lh*4+r, e'=nt*16+l15; seeded with bo.
  f32x4 oacc[2][2];
  {
    float b0 = bo[l15], b1 = bo[16 + l15];
#pragma unroll
    for (int mt = 0; mt < 2; ++mt) {
      oacc[mt][0] = f32x4{b0, b0, b0, b0};
      oacc[mt][1] = f32x4{b1, b1, b1, b1};
    }
  }

  // t A-frags (scores), packed straight from t-proj MFMA output regs.
  bf16x8 tka0, tka1;

  // Per head: t-proj (wave-local, reg-packed) + v-proj (vT staged cross-wave).
  auto do_proj = [&](int hh, int vo) {
    const __bf16* Mh = wbf + hh * 1024;
    bf16x8 m0 = *(const bf16x8*)&Mh[(l15) * 32 + lh * 8];       // e' rows 0-15
    bf16x8 m1 = *(const bf16x8*)&Mh[(16 + l15) * 32 + lh * 8];  // e' rows 16-31
    // t^T[e'][j] = mfma(M, xn_own): D cols = j = l15(+st*16), rows = e' reg-held.
    f32x4 d00 = __builtin_amdgcn_mfma_f32_16x16x32_bf16(m0, tA0, fz, 0, 0, 0);
    f32x4 d01 = __builtin_amdgcn_mfma_f32_16x16x32_bf16(m0, tA1, fz, 0, 0, 0);
    f32x4 d10 = __builtin_amdgcn_mfma_f32_16x16x32_bf16(m1, tA0, fz, 0, 0, 0);
    f32x4 d11 = __builtin_amdgcn_mfma_f32_16x16x32_bf16(m1, tA1, fz, 0, 0, 0);
    // tka_st[u] = t[j=r0+st*16+l15][e'(u)], e'(u) = (u>=4)*16 + lh*4 + (u&3).
#pragma unroll
    for (int u = 0; u < 4; ++u) {
      tka0[u] = (__bf16)d00[u]; tka0[4 + u] = (__bf16)d10[u];
      tka1[u] = (__bf16)d01[u]; tka1[4 + u] = (__bf16)d11[u];
    }
    // v-proj: D[s][f], packed store into swizzled vT[f][s].
#pragma unroll
    for (int nt = 0; nt < 2; ++nt) {
      int f0 = hh * 32 + nt * 16;
      bf16x8 wvf = *(const bf16x8*)&wvb[(f0 + l15) * 32 + lh * 8];
      float bvs = bv[f0 + l15];
      f32x4 bv4 = {bvs, bvs, bvs, bvs};
#pragma unroll
      for (int mt = 0; mt < 2; ++mt) {
        bf16x8 tA = (mt == 0) ? tA0 : tA1;
        f32x4 dv = __builtin_amdgcn_mfma_f32_16x16x32_bf16(tA, wvf, bv4, 0, 0, 0);
        bf16x4 pv;
#pragma unroll
        for (int r = 0; r < 4; ++r) pv[r] = (__bf16)dv[r];
        *(bf16x4*)&R[vo + (nt * 16 + l15) * 128 + ((r0 + mt * 16 + lh * 4) ^ sw)] = pv;
      }
    }
  };

  do_proj(0, V0);
  __syncthreads();  // P2: s + vT[0] visible

  for (int h = 0; h < NH; ++h) {
    const int p = h & 1;
    const int vo = p ? V1 : V0;

    // ---------- [1] scoresT = t·xn^T : 100% register operands ----------
    // st_[mt][it]: D[j][i], j = r0+mt*16+lh*4+r, i = it*16+l15
    f32x4 st_[2][8];
#pragma unroll
    for (int it = 0; it < 8; ++it) {
      st_[0][it] = __builtin_amdgcn_mfma_f32_16x16x32_bf16(tka0, xq[it], fz, 0, 0, 0);
      st_[1][it] = __builtin_amdgcn_mfma_f32_16x16x32_bf16(tka1, xq[it], fz, 0, 0, 0);
    }

    // ---------- [2] project NEXT head (fills scores MFMA latency) ----------
    if (h < NH - 1) do_proj(h + 1, p ? V0 : V1);

    // ---------- [3] softmax over query axis: + s_i bias, exp2, DPP sums ----------
    float sv[8];
#pragma unroll
    for (int it = 0; it < 8; ++it) sv[it] = sp[h * 128 + it * 16 + l15];
    float inv[2][4];
#pragma unroll
    for (int mt = 0; mt < 2; ++mt)
#pragma unroll
      for (int r = 0; r < 4; ++r) {
        float ssum = 0.f;
#pragma unroll
        for (int it = 0; it < 8; ++it) {
          float e = __builtin_amdgcn_exp2f(st_[mt][it][r] + sv[it]);
          st_[mt][it][r] = e;
          ssum += e;
        }
        ssum = row_reduce_add16(ssum);
        inv[mt][r] = __builtin_amdgcn_rcpf(ssum);
      }

    __syncthreads();  // A: PV(h-1) P-reads done; vT[p] stores visible

    // ---------- [4] va prefetch (vT[p] stable since before A) ----------
    bf16x8 va[2][4];
#pragma unroll
    for (int kc = 0; kc < 4; ++kc) {
      va[0][kc] = *(const bf16x8*)&R[vo + (l15) * 128 + ((kc * 32 + lh * 8) ^ sw)];
      va[1][kc] = *(const bf16x8*)&R[vo + (16 + l15) * 128 + ((kc * 32 + lh * 8) ^ sw)];
    }

    // ---------- [5] P store: normalized, [query][key] swizzled, packed b64 ----------
#pragma unroll
    for (int mt = 0; mt < 2; ++mt)
#pragma unroll
      for (int it = 0; it < 8; ++it) {
        bf16x4 pp;
#pragma unroll
        for (int r = 0; r < 4; ++r) pp[r] = (__bf16)(st_[mt][it][r] * inv[mt][r]);
        *(bf16x4*)&R[PO + (it * 16 + l15) * 128 + ((r0 + mt * 16 + lh * 4) ^ sw)] = pp;
      }
    __syncthreads();  // B: P ready

    // ---------- [6] PV: D[e][q] = vT·P^T ----------
    f32x4 p2[2][2];
#pragma unroll
    for (int i = 0; i < 2; ++i)
#pragma unroll
      for (int j = 0; j < 2; ++j) p2[i][j] = fz;
#pragma unroll
    for (int kc = 0; kc < 4; ++kc) {
      bf16x8 pb0 = *(const bf16x8*)&R[PO + (r0 + l15) * 128 + ((kc * 32 + lh * 8) ^ sw)];
      bf16x8 pb1 = *(const bf16x8*)&R[PO + (r0 + 16 + l15) * 128 + ((kc * 32 + lh * 8) ^ sw)];
      p2[0][0] = __builtin_amdgcn_mfma_f32_16x16x32_bf16(va[0][kc], pb0, p2[0][0], 0, 0, 0);
      p2[0][1] = __builtin_amdgcn_mfma_f32_16x16x32_bf16(va[0][kc], pb1, p2[0][1], 0, 0, 0);
      p2[1][0] = __builtin_amdgcn_mfma_f32_16x16x32_bf16(va[1][kc], pb0, p2[1][0], 0, 0, 0);
      p2[1][1] = __builtin_amdgcn_mfma_f32_16x16x32_bf16(va[1][kc], pb1, p2[1][1], 0, 0, 0);
    }

    // ---------- [7] outproj from registers (permuted-k, no LDS) ----------
    // virtual k u <-> e = (u>=4)*16 + lh*4 + (u&3); A and B share it.
    {
      bf16x8 pa0, pa1;
#pragma unroll
      for (int u = 0; u < 4; ++u) {
        pa0[u] = (__bf16)p2[0][0][u]; pa0[4 + u] = (__bf16)p2[1][0][u];
        pa1[u] = (__bf16)p2[0][1][u]; pa1[4 + u] = (__bf16)p2[1][1][u];
      }
      bf16x4 w0lo = *(const bf16x4*)&wob[(l15) * 256 + h * 32 + lh * 4];
      bf16x4 w0hi = *(const bf16x4*)&wob[(l15) * 256 + h * 32 + 16 + lh * 4];
      bf16x4 w1lo = *(const bf16x4*)&wob[(16 + l15) * 256 + h * 32 + lh * 4];
      bf16x4 w1hi = *(const bf16x4*)&wob[(16 + l15) * 256 + h * 32 + 16 + lh * 4];
      bf16x8 wof0, wof1;
#pragma unroll
      for (int u = 0; u < 4; ++u) {
        wof0[u] = w0lo[u]; wof0[4 + u] = w0hi[u];
        wof1[u] = w1lo[u]; wof1[4 + u] = w1hi[u];
      }
      oacc[0][0] = __builtin_amdgcn_mfma_f32_16x16x32_bf16(pa0, wof0, oacc[0][0], 0, 0, 0);
      oacc[0][1] = __builtin_amdgcn_mfma_f32_16x16x32_bf16(pa0, wof1, oacc[0][1], 0, 0, 0);
      oacc[1][0] = __builtin_amdgcn_mfma_f32_16x16x32_bf16(pa1, wof0, oacc[1][0], 0, 0, 0);
      oacc[1][1] = __builtin_amdgcn_mfma_f32_16x16x32_bf16(pa1, wof1, oacc[1][1], 0, 0, 0);
    }
    // No trailing barrier: barrier A(h+1) separates PV(h) P-reads from
    // P-stores(h+1); vT double-buffered across two barriers.
  }

  // ---------------- epilogue: + x (bo already seeded) ----------------
#pragma unroll
  for (int mt = 0; mt < 2; ++mt)
#pragma unroll
    for (int nt = 0; nt < 2; ++nt)
#pragma unroll
      for (int r = 0; r < 4; ++r) {
        int s_ = r0 + mt * 16 + lh * 4 + r;
        int e_ = nt * 16 + l15;
        int idx = s_ * 32 + e_;
        out[b * INSZ + idx] = oacc[mt][nt][r] + xb[idx];
      }
}

extern "C" void kernel_launch(void* const* d_in, const int* in_sizes, int n_in,
                              void* d_out, int out_size, void* d_ws, size_t ws_size,
                              hipStream_t stream) {
  const float* x = (const float*)d_in[0];
  const float* gamma = (const float*)d_in[1];
  const float* beta = (const float*)d_in[2];
  const float* wq = (const float*)d_in[3];
  const float* wk = (const float*)d_in[5];
  const float* bk = (const float*)d_in[6];
  const float* wv = (const float*)d_in[7];
  const float* bv = (const float*)d_in[8];
  const float* wo = (const float*)d_in[9];
  const float* bo = (const float*)d_in[10];
  float* out = (float*)d_out;
  __bf16* wsb = (__bf16*)d_ws;

  prep<<<72, TPB, 0, stream>>>(wq, wk, bk, wv, wo, wsb);
  mha_fused<<<BATCH, TPB, 0, stream>>>(x, gamma, beta, bv, bo, wsb, out);
}